// Round 13
// baseline (117.158 us; speedup 1.0000x reference)
//
#include <hip/hip_runtime.h>
#include <math.h>

#define T_LEN 1024
#define VV 512
#define VVh 256
#define BB 64
#define NB 16
#define ANG_STEP 0.006135923151542565f   // 2*pi/1024
#define FADE_S 487
#define FADE_E 537
#define ATL 64

typedef float v2f __attribute__((ext_vector_type(2)));   // native vec for nontemporal builtins

__device__ constexpr int KB[NB] = {1,2,3,4,5,6,7,8,12,16,24,32,48,64,96,128};

// ---------------- Kernel 1: partial 16-bin DFT over a t-chunk ----------------
// grid (BB, TC), block 256, thread owns v0=2*tid, v0+1 (VPT=2).
// cs from per-block LDS table (broadcast ds_read_b64 on LDS pipe hides under
// 64 fma-inst/t on VALU pipe). 8-deep prefetch. Partials written NON-TEMPORAL:
// single-use data must not evict x from L3 (x is re-read by k_apply).
// Partials: xp[((b*TC + tc)*32 + q)*VV + v], q in [0,16)=re_j, [16,32)=im_j
template<int TLEN>
__global__ __launch_bounds__(256, 2) void k_dft_partial(const float* __restrict__ x,
                                                        float* __restrict__ xpart,
                                                        int tc_count) {
    const int b   = blockIdx.x;
    const int tc  = blockIdx.y;
    const int tid = threadIdx.x;
    const int t0  = tc * TLEN;

    __shared__ float2 tab[TLEN][NB];
    for (int i = tid; i < TLEN * NB; i += 256) {
        int t = i >> 4, j = i & 15;
        int idx = (KB[j] * (t0 + t)) & (T_LEN - 1);
        float ss, cc; sincosf(ANG_STEP * (float)idx, &ss, &cc);
        tab[t][j] = make_float2(cc, ss);
    }
    __syncthreads();

    float xr0[NB], xi0[NB], xr1[NB], xi1[NB];
#pragma unroll
    for (int j = 0; j < NB; ++j) { xr0[j] = xi0[j] = xr1[j] = xi1[j] = 0.0f; }

    const float2* xrd = (const float2*)(x + ((size_t)b * T_LEN + t0) * VV) + tid;

#define DFT_T(TT, AV)                                           \
    do {                                                        \
        _Pragma("unroll")                                       \
        for (int j = 0; j < NB; ++j) {                          \
            float2 cs = tab[(TT)][j];                           \
            xr0[j] = fmaf((AV).x, cs.x, xr0[j]);                \
            xi0[j] = fmaf(-(AV).x, cs.y, xi0[j]);               \
            xr1[j] = fmaf((AV).y, cs.x, xr1[j]);                \
            xi1[j] = fmaf(-(AV).y, cs.y, xi1[j]);               \
        }                                                       \
    } while (0)

    // 8-deep software-pipelined prefetch
    float2 a0 = xrd[(size_t)0 * VVh];
    float2 a1 = xrd[(size_t)1 * VVh];
    float2 a2 = xrd[(size_t)2 * VVh];
    float2 a3 = xrd[(size_t)3 * VVh];
    float2 a4 = xrd[(size_t)4 * VVh];
    float2 a5 = xrd[(size_t)5 * VVh];
    float2 a6 = xrd[(size_t)6 * VVh];
    float2 a7 = xrd[(size_t)7 * VVh];
#pragma unroll 1
    for (int t = 0; t < TLEN - 8; t += 8) {
        float2 b0 = xrd[(size_t)(t +  8) * VVh];
        float2 b1 = xrd[(size_t)(t +  9) * VVh];
        float2 b2 = xrd[(size_t)(t + 10) * VVh];
        float2 b3 = xrd[(size_t)(t + 11) * VVh];
        float2 b4 = xrd[(size_t)(t + 12) * VVh];
        float2 b5 = xrd[(size_t)(t + 13) * VVh];
        float2 b6 = xrd[(size_t)(t + 14) * VVh];
        float2 b7 = xrd[(size_t)(t + 15) * VVh];
        DFT_T(t + 0, a0); DFT_T(t + 1, a1); DFT_T(t + 2, a2); DFT_T(t + 3, a3);
        DFT_T(t + 4, a4); DFT_T(t + 5, a5); DFT_T(t + 6, a6); DFT_T(t + 7, a7);
        a0 = b0; a1 = b1; a2 = b2; a3 = b3;
        a4 = b4; a5 = b5; a6 = b6; a7 = b7;
    }
    {
        const int t = TLEN - 8;
        DFT_T(t + 0, a0); DFT_T(t + 1, a1); DFT_T(t + 2, a2); DFT_T(t + 3, a3);
        DFT_T(t + 4, a4); DFT_T(t + 5, a5); DFT_T(t + 6, a6); DFT_T(t + 7, a7);
    }
#undef DFT_T

    v2f* o = (v2f*)(xpart + (size_t)(b * tc_count + tc) * 32 * VV) + tid;
#pragma unroll
    for (int j = 0; j < NB; ++j) {
        v2f re; re.x = xr0[j]; re.y = xr1[j];
        v2f im; im.x = xi0[j]; im.y = xi1[j];
        __builtin_nontemporal_store(re, &o[(size_t)j        * VVh]);
        __builtin_nontemporal_store(im, &o[(size_t)(NB + j) * VVh]);
    }
}

// ---------------- Kernel 2: reduce partials, apply gains -> H ----------------
// grid (BB, NB): one j-bin per block (1024 blocks). Partials read NON-TEMPORAL
// (single-use). H stored normally (re-read 16x by k_apply -> keep cached).
// H layout: H[b][q][v], q: [0,16)=He_re, [16,32)=-He_im, [32,48)=Hl_re, [48,64)=-Hl_im
__global__ __launch_bounds__(256) void k_combine(const float* __restrict__ xpart,
                                                 const float* __restrict__ ger,
                                                 const float* __restrict__ gei,
                                                 const float* __restrict__ glr,
                                                 const float* __restrict__ gli,
                                                 float* __restrict__ H, int tc_count) {
    const int b   = blockIdx.x;
    const int j   = blockIdx.y;
    const int tid = threadIdx.x;
    const int v0  = tid * 2;

    float re0 = 0.f, re1 = 0.f, im0 = 0.f, im1 = 0.f;
#pragma unroll 8
    for (int tc = 0; tc < tc_count; ++tc) {
        const v2f* p = (const v2f*)(xpart + (size_t)(b * tc_count + tc) * 32 * VV) + tid;
        v2f a  = __builtin_nontemporal_load(&p[(size_t)j        * VVh]);
        v2f bb = __builtin_nontemporal_load(&p[(size_t)(NB + j) * VVh]);
        re0 += a.x;  re1 += a.y;
        im0 += bb.x; im1 += bb.y;
    }

    const float scale = 2.0f / (float)T_LEN;
    float er0 = ger[v0 * NB + j],       ei0 = gei[v0 * NB + j];
    float lr0 = glr[v0 * NB + j],       li0 = gli[v0 * NB + j];
    float er1 = ger[(v0 + 1) * NB + j], ei1 = gei[(v0 + 1) * NB + j];
    float lr1 = glr[(v0 + 1) * NB + j], li1 = gli[(v0 + 1) * NB + j];

    float here0 = (re0 * er0 - im0 * ei0) * scale;
    float heim0 = (re0 * ei0 + im0 * er0) * scale;
    float hlre0 = (re0 * lr0 - im0 * li0) * scale;
    float hlim0 = (re0 * li0 + im0 * lr0) * scale;
    float here1 = (re1 * er1 - im1 * ei1) * scale;
    float heim1 = (re1 * ei1 + im1 * er1) * scale;
    float hlre1 = (re1 * lr1 - im1 * li1) * scale;
    float hlim1 = (re1 * li1 + im1 * lr1) * scale;

    float2* o = (float2*)(H + (size_t)b * 64 * VV) + tid;
    o[(size_t)j        * VVh] = make_float2(here0, here1);
    o[(size_t)(16 + j) * VVh] = make_float2(-heim0, -heim1);
    o[(size_t)(32 + j) * VVh] = make_float2(hlre0, hlre1);
    o[(size_t)(48 + j) * VVh] = make_float2(-hlim0, -hlim1);
}

// ---------------- Kernel 3: uniform apply, single H set per tile ----------------
// grid (BB, 16), block 256, VPT=2. He for tiles 0..7, Hl for 8..15.
// Fade rows 487..536 get overwritten by k_fixup afterwards.
// Non-temporal stores: out is write-only; keep L2/L3 for x.
__global__ __launch_bounds__(256, 2) void k_apply(const float* __restrict__ x,
                                                  const float* __restrict__ H,
                                                  float* __restrict__ out) {
    const int b    = blockIdx.x;
    const int tile = blockIdx.y;
    const int tid  = threadIdx.x;
    const int t0   = tile * ATL;
    const int qo   = (tile < 8) ? 0 : 32;

    __shared__ float2 tab[ATL][NB];
    for (int i = tid; i < ATL * NB; i += 256) {
        int t = i >> 4, j = i & 15;
        int idx = (KB[j] * (t0 + t)) & (T_LEN - 1);
        float ss, cc; sincosf(ANG_STEP * (float)idx, &ss, &cc);
        tab[t][j] = make_float2(cc, ss);
    }

    float hr0[NB], hi0[NB], hr1[NB], hi1[NB];
    const float2* hp = (const float2*)(H + (size_t)b * 64 * VV) + tid;
#pragma unroll
    for (int j = 0; j < NB; ++j) {
        float2 a  = hp[(size_t)(qo + j)      * VVh]; hr0[j] = a.x;  hr1[j] = a.y;
        float2 bq = hp[(size_t)(qo + 16 + j) * VVh]; hi0[j] = bq.x; hi1[j] = bq.y;
    }
    __syncthreads();

    const float2* xrd = (const float2*)(x + ((size_t)b * T_LEN + t0) * VV) + tid;
    v2f*          ow  = (v2f*)(out + ((size_t)b * T_LEN + t0) * VV) + tid;

#define APPLY_T(TT, AV)                                         \
    do {                                                        \
        float s0 = 0.f, s1 = 0.f;                               \
        _Pragma("unroll")                                       \
        for (int j = 0; j < NB; ++j) {                          \
            float2 cs = tab[(TT)][j];                           \
            s0 = fmaf(hr0[j], cs.x, s0);                        \
            s0 = fmaf(hi0[j], cs.y, s0);                        \
            s1 = fmaf(hr1[j], cs.x, s1);                        \
            s1 = fmaf(hi1[j], cs.y, s1);                        \
        }                                                       \
        v2f ov; ov.x = (AV).x + s0; ov.y = (AV).y + s1;         \
        __builtin_nontemporal_store(ov,                         \
            &ow[(size_t)(TT) * VVh]);                           \
    } while (0)

    float2 a0 = xrd[(size_t)0 * VVh];
    float2 a1 = xrd[(size_t)1 * VVh];
    float2 a2 = xrd[(size_t)2 * VVh];
    float2 a3 = xrd[(size_t)3 * VVh];
    float2 a4 = xrd[(size_t)4 * VVh];
    float2 a5 = xrd[(size_t)5 * VVh];
    float2 a6 = xrd[(size_t)6 * VVh];
    float2 a7 = xrd[(size_t)7 * VVh];
#pragma unroll 1
    for (int t = 0; t < ATL - 8; t += 8) {
        float2 b0 = xrd[(size_t)(t +  8) * VVh];
        float2 b1 = xrd[(size_t)(t +  9) * VVh];
        float2 b2 = xrd[(size_t)(t + 10) * VVh];
        float2 b3 = xrd[(size_t)(t + 11) * VVh];
        float2 b4 = xrd[(size_t)(t + 12) * VVh];
        float2 b5 = xrd[(size_t)(t + 13) * VVh];
        float2 b6 = xrd[(size_t)(t + 14) * VVh];
        float2 b7 = xrd[(size_t)(t + 15) * VVh];
        APPLY_T(t + 0, a0); APPLY_T(t + 1, a1); APPLY_T(t + 2, a2); APPLY_T(t + 3, a3);
        APPLY_T(t + 4, a4); APPLY_T(t + 5, a5); APPLY_T(t + 6, a6); APPLY_T(t + 7, a7);
        a0 = b0; a1 = b1; a2 = b2; a3 = b3;
        a4 = b4; a5 = b5; a6 = b6; a7 = b7;
    }
    {
        const int t = ATL - 8;
        APPLY_T(t + 0, a0); APPLY_T(t + 1, a1); APPLY_T(t + 2, a2); APPLY_T(t + 3, a3);
        APPLY_T(t + 4, a4); APPLY_T(t + 5, a5); APPLY_T(t + 6, a6); APPLY_T(t + 7, a7);
    }
#undef APPLY_T
}

// ---------------- Kernel 4: fade fixup, rows 487..536 only ----------------
// grid (BB, 2), block 512, thread owns v = tid. tz=0 -> rows 487..511,
// tz=1 -> rows 512..536. Recomputes the exact dual-H crossfade formula.
__global__ __launch_bounds__(512) void k_fixup(const float* __restrict__ x,
                                               const float* __restrict__ H,
                                               float* __restrict__ out) {
    const int b   = blockIdx.x;
    const int tz  = blockIdx.y;
    const int tid = threadIdx.x;
    const int ts  = tz ? 512 : FADE_S;        // start row
    const int te  = tz ? FADE_E : 512;        // end row (exclusive)
    const int nt  = te - ts;                   // 25 rows each

    __shared__ float2 tab[32][NB];             // up to 25 rows used
    for (int i = tid; i < nt * NB; i += 512) {
        int t = i >> 4, j = i & 15;
        int idx = (KB[j] * (ts + t)) & (T_LEN - 1);
        float ss, cc; sincosf(ANG_STEP * (float)idx, &ss, &cc);
        tab[t][j] = make_float2(cc, ss);
    }

    float er[NB], ei[NB], lr[NB], li[NB];
    const float* hp = H + (size_t)b * 64 * VV + tid;
#pragma unroll
    for (int j = 0; j < NB; ++j) {
        er[j] = hp[(size_t)j        * VV];
        ei[j] = hp[(size_t)(16 + j) * VV];
        lr[j] = hp[(size_t)(32 + j) * VV];
        li[j] = hp[(size_t)(48 + j) * VV];
    }
    __syncthreads();

    const float* xrd = x + ((size_t)b * T_LEN + ts) * VV + tid;
    float*       ow  = out + ((size_t)b * T_LEN + ts) * VV + tid;

    for (int t = 0; t < nt; ++t) {
        float av = xrd[(size_t)t * VV];
        const int tg = ts + t;
        float se = 0.f, sl = 0.f;
#pragma unroll
        for (int j = 0; j < NB; ++j) {
            float2 cs = tab[t][j];
            se = fmaf(er[j], cs.x, se); se = fmaf(ei[j], cs.y, se);
            sl = fmaf(lr[j], cs.x, sl); sl = fmaf(li[j], cs.y, sl);
        }
        float w = 1.0f - (float)(tg - FADE_S) * (1.0f / 50.0f);
        ow[(size_t)t * VV] = av + fmaf(w, se - sl, sl);
    }
}

extern "C" void kernel_launch(void* const* d_in, const int* in_sizes, int n_in,
                              void* d_out, int out_size, void* d_ws, size_t ws_size,
                              hipStream_t stream) {
    (void)in_sizes; (void)n_in; (void)out_size;
    const float* x   = (const float*)d_in[0];
    const float* ger = (const float*)d_in[1];
    const float* gei = (const float*)d_in[2];
    const float* glr = (const float*)d_in[3];
    const float* gli = (const float*)d_in[4];
    float* out = (float*)d_out;

    // ws layout: partials | H
    const size_t hflts = (size_t)BB * 64 * VV;
    int TC;
    if (((size_t)BB * 8 * 32 * VV + hflts) * sizeof(float) <= ws_size)  TC = 8;
    else                                                                TC = 4;

    float* xpart = (float*)d_ws;
    float* H     = xpart + (size_t)BB * TC * 32 * VV;

    if (TC == 8) k_dft_partial<128><<<dim3(BB, 8), 256, 0, stream>>>(x, xpart, 8);
    else         k_dft_partial<256><<<dim3(BB, 4), 256, 0, stream>>>(x, xpart, 4);

    k_combine<<<dim3(BB, NB), 256, 0, stream>>>(xpart, ger, gei, glr, gli, H, TC);
    k_apply<<<dim3(BB, 16), 256, 0, stream>>>(x, H, out);
    k_fixup<<<dim3(BB, 2), 512, 0, stream>>>(x, H, out);
}

// Round 14
// 114.942 us; speedup vs baseline: 1.0193x; 1.0193x over previous
//
#include <hip/hip_runtime.h>
#include <math.h>

#define T_LEN 1024
#define VV 512
#define BB 64
#define NB 16
#define ANG_STEP 0.006135923151542565f   // 2*pi/1024
#define FADE_S 487
#define FADE_E 537
#define ATL 64

typedef float v4f __attribute__((ext_vector_type(4)));   // native vec for nontemporal stores

__device__ constexpr int KB[NB] = {1,2,3,4,5,6,7,8,12,16,24,32,48,64,96,128};

// ---------------- Kernel 1: partial 16-bin DFT, VPT=4 ----------------
// grid (BB, TC), block 256 = 2 half-groups x 128 lanes. Lane owns v0=lane*4.
// Half h covers t-rows [t0 + h*TLEN/2, +TLEN/2), writes partial chunk tc*2+h.
// VPT=4 halves wave count -> LDS broadcast-read issue (the R12 bottleneck,
// ~41us) drops to ~20us, hidden under memory + VALU.
// Partials: xp[((b*tcx_count + tcx)*32 + q)*VV + v], q in [0,16)=re_j, [16,32)=im_j
template<int TLEN>
__global__ __launch_bounds__(256, 2) void k_dft_partial(const float* __restrict__ x,
                                                        float* __restrict__ xpart,
                                                        int tcx_count) {
    const int b    = blockIdx.x;
    const int tc   = blockIdx.y;
    const int tid  = threadIdx.x;
    const int h    = tid >> 7;
    const int lane = tid & 127;
    const int t0   = tc * TLEN;
    const int HT   = TLEN / 2;

    __shared__ float2 tab[TLEN][NB];
    for (int i = tid; i < TLEN * NB; i += 256) {
        int t = i >> 4, j = i & 15;
        int idx = (KB[j] * (t0 + t)) & (T_LEN - 1);
        float ss, cc; sincosf(ANG_STEP * (float)idx, &ss, &cc);
        tab[t][j] = make_float2(cc, ss);
    }
    __syncthreads();

    float xr0[NB], xi0[NB], xr1[NB], xi1[NB];
    float xr2[NB], xi2[NB], xr3[NB], xi3[NB];
#pragma unroll
    for (int j = 0; j < NB; ++j) {
        xr0[j] = xi0[j] = xr1[j] = xi1[j] = 0.0f;
        xr2[j] = xi2[j] = xr3[j] = xi3[j] = 0.0f;
    }

    const int th0 = h * HT;                      // local row offset of this half
    const float4* xrd = (const float4*)(x + ((size_t)b * T_LEN + t0 + th0) * VV) + lane;
    // row stride in float4 units = VV/4 = 128

#define DFT_T(TT, AV)                                           \
    do {                                                        \
        _Pragma("unroll")                                       \
        for (int j = 0; j < NB; ++j) {                          \
            float2 cs = tab[th0 + (TT)][j];                     \
            xr0[j] = fmaf((AV).x, cs.x, xr0[j]);                \
            xi0[j] = fmaf(-(AV).x, cs.y, xi0[j]);               \
            xr1[j] = fmaf((AV).y, cs.x, xr1[j]);                \
            xi1[j] = fmaf(-(AV).y, cs.y, xi1[j]);               \
            xr2[j] = fmaf((AV).z, cs.x, xr2[j]);                \
            xi2[j] = fmaf(-(AV).z, cs.y, xi2[j]);               \
            xr3[j] = fmaf((AV).w, cs.x, xr3[j]);                \
            xi3[j] = fmaf(-(AV).w, cs.y, xi3[j]);               \
        }                                                       \
    } while (0)

    // 4-deep software-pipelined prefetch (4 steps x 256 VALU cy > HBM latency)
    float4 a0 = xrd[(size_t)0 * 128];
    float4 a1 = xrd[(size_t)1 * 128];
    float4 a2 = xrd[(size_t)2 * 128];
    float4 a3 = xrd[(size_t)3 * 128];
#pragma unroll 1
    for (int t = 0; t < HT - 4; t += 4) {
        float4 b0 = xrd[(size_t)(t + 4) * 128];
        float4 b1 = xrd[(size_t)(t + 5) * 128];
        float4 b2 = xrd[(size_t)(t + 6) * 128];
        float4 b3 = xrd[(size_t)(t + 7) * 128];
        DFT_T(t + 0, a0); DFT_T(t + 1, a1); DFT_T(t + 2, a2); DFT_T(t + 3, a3);
        a0 = b0; a1 = b1; a2 = b2; a3 = b3;
    }
    {
        const int t = HT - 4;
        DFT_T(t + 0, a0); DFT_T(t + 1, a1); DFT_T(t + 2, a2); DFT_T(t + 3, a3);
    }
#undef DFT_T

    const int tcx = tc * 2 + h;
    float4* o = (float4*)(xpart + (size_t)(b * tcx_count + tcx) * 32 * VV) + lane;
#pragma unroll
    for (int j = 0; j < NB; ++j) {
        o[(size_t)j        * 128] = make_float4(xr0[j], xr1[j], xr2[j], xr3[j]);
        o[(size_t)(NB + j) * 128] = make_float4(xi0[j], xi1[j], xi2[j], xi3[j]);
    }
}

// ---------------- Kernel 2: reduce partials, apply gains -> H ----------------
// grid (BB, NB): one j-bin per block (1024 blocks).
// H layout: H[b][q][v], q: [0,16)=He_re, [16,32)=-He_im, [32,48)=Hl_re, [48,64)=-Hl_im
// (ims pre-negated: apply computes hr*cos + hi*sin = Hre*cos - Him*sin.)
__global__ __launch_bounds__(256) void k_combine(const float* __restrict__ xpart,
                                                 const float* __restrict__ ger,
                                                 const float* __restrict__ gei,
                                                 const float* __restrict__ glr,
                                                 const float* __restrict__ gli,
                                                 float* __restrict__ H, int tc_count) {
    const int b   = blockIdx.x;
    const int j   = blockIdx.y;
    const int tid = threadIdx.x;
    const int v0  = tid * 2;

    float re0 = 0.f, re1 = 0.f, im0 = 0.f, im1 = 0.f;
#pragma unroll 8
    for (int tc = 0; tc < tc_count; ++tc) {
        const float2* p = (const float2*)(xpart + (size_t)(b * tc_count + tc) * 32 * VV) + tid;
        float2 a  = p[(size_t)j        * 256];
        float2 bb = p[(size_t)(NB + j) * 256];
        re0 += a.x;  re1 += a.y;
        im0 += bb.x; im1 += bb.y;
    }

    const float scale = 2.0f / (float)T_LEN;
    float er0 = ger[v0 * NB + j],       ei0 = gei[v0 * NB + j];
    float lr0 = glr[v0 * NB + j],       li0 = gli[v0 * NB + j];
    float er1 = ger[(v0 + 1) * NB + j], ei1 = gei[(v0 + 1) * NB + j];
    float lr1 = glr[(v0 + 1) * NB + j], li1 = gli[(v0 + 1) * NB + j];

    float here0 = (re0 * er0 - im0 * ei0) * scale;
    float heim0 = (re0 * ei0 + im0 * er0) * scale;
    float hlre0 = (re0 * lr0 - im0 * li0) * scale;
    float hlim0 = (re0 * li0 + im0 * lr0) * scale;
    float here1 = (re1 * er1 - im1 * ei1) * scale;
    float heim1 = (re1 * ei1 + im1 * er1) * scale;
    float hlre1 = (re1 * lr1 - im1 * li1) * scale;
    float hlim1 = (re1 * li1 + im1 * lr1) * scale;

    float2* o = (float2*)(H + (size_t)b * 64 * VV) + tid;
    o[(size_t)j        * 256] = make_float2(here0, here1);
    o[(size_t)(16 + j) * 256] = make_float2(-heim0, -heim1);
    o[(size_t)(32 + j) * 256] = make_float2(hlre0, hlre1);
    o[(size_t)(48 + j) * 256] = make_float2(-hlim0, -hlim1);
}

// ---------------- Kernel 3: uniform apply, VPT=4 ----------------
// grid (BB, 16), block 128, lane owns v0=tid*4. He for tiles 0..7, Hl for 8..15.
// Fade rows 487..536 get overwritten by k_fixup afterwards.
// Non-temporal out stores (write-only). VPT=4 halves LDS broadcast-read issue.
__global__ __launch_bounds__(128, 2) void k_apply(const float* __restrict__ x,
                                                  const float* __restrict__ H,
                                                  float* __restrict__ out) {
    const int b    = blockIdx.x;
    const int tile = blockIdx.y;
    const int tid  = threadIdx.x;
    const int t0   = tile * ATL;
    const int qo   = (tile < 8) ? 0 : 32;

    __shared__ float2 tab[ATL][NB];
    for (int i = tid; i < ATL * NB; i += 128) {
        int t = i >> 4, j = i & 15;
        int idx = (KB[j] * (t0 + t)) & (T_LEN - 1);
        float ss, cc; sincosf(ANG_STEP * (float)idx, &ss, &cc);
        tab[t][j] = make_float2(cc, ss);
    }

    float hr0[NB], hi0[NB], hr1[NB], hi1[NB];
    float hr2[NB], hi2[NB], hr3[NB], hi3[NB];
    const float4* hp = (const float4*)(H + (size_t)b * 64 * VV) + tid;
#pragma unroll
    for (int j = 0; j < NB; ++j) {
        float4 a  = hp[(size_t)(qo + j)      * 128];
        hr0[j] = a.x;  hr1[j] = a.y;  hr2[j] = a.z;  hr3[j] = a.w;
        float4 bq = hp[(size_t)(qo + 16 + j) * 128];
        hi0[j] = bq.x; hi1[j] = bq.y; hi2[j] = bq.z; hi3[j] = bq.w;
    }
    __syncthreads();

    const float4* xrd = (const float4*)(x + ((size_t)b * T_LEN + t0) * VV) + tid;
    v4f*          ow  = (v4f*)(out + ((size_t)b * T_LEN + t0) * VV) + tid;

#define APPLY_T(TT, AV)                                         \
    do {                                                        \
        float s0 = 0.f, s1 = 0.f, s2 = 0.f, s3 = 0.f;           \
        _Pragma("unroll")                                       \
        for (int j = 0; j < NB; ++j) {                          \
            float2 cs = tab[(TT)][j];                           \
            s0 = fmaf(hr0[j], cs.x, s0);                        \
            s0 = fmaf(hi0[j], cs.y, s0);                        \
            s1 = fmaf(hr1[j], cs.x, s1);                        \
            s1 = fmaf(hi1[j], cs.y, s1);                        \
            s2 = fmaf(hr2[j], cs.x, s2);                        \
            s2 = fmaf(hi2[j], cs.y, s2);                        \
            s3 = fmaf(hr3[j], cs.x, s3);                        \
            s3 = fmaf(hi3[j], cs.y, s3);                        \
        }                                                       \
        v4f ov; ov.x = (AV).x + s0; ov.y = (AV).y + s1;         \
        ov.z = (AV).z + s2; ov.w = (AV).w + s3;                 \
        __builtin_nontemporal_store(ov,                         \
            &ow[(size_t)(TT) * 128]);                           \
    } while (0)

    float4 a0 = xrd[(size_t)0 * 128];
    float4 a1 = xrd[(size_t)1 * 128];
    float4 a2 = xrd[(size_t)2 * 128];
    float4 a3 = xrd[(size_t)3 * 128];
#pragma unroll 1
    for (int t = 0; t < ATL - 4; t += 4) {
        float4 b0 = xrd[(size_t)(t + 4) * 128];
        float4 b1 = xrd[(size_t)(t + 5) * 128];
        float4 b2 = xrd[(size_t)(t + 6) * 128];
        float4 b3 = xrd[(size_t)(t + 7) * 128];
        APPLY_T(t + 0, a0); APPLY_T(t + 1, a1); APPLY_T(t + 2, a2); APPLY_T(t + 3, a3);
        a0 = b0; a1 = b1; a2 = b2; a3 = b3;
    }
    {
        const int t = ATL - 4;
        APPLY_T(t + 0, a0); APPLY_T(t + 1, a1); APPLY_T(t + 2, a2); APPLY_T(t + 3, a3);
    }
#undef APPLY_T
}

// ---------------- Kernel 4: fade fixup, rows 487..536 only ----------------
// grid (BB, 2), block 512, thread owns v = tid. Exact dual-H crossfade.
__global__ __launch_bounds__(512) void k_fixup(const float* __restrict__ x,
                                               const float* __restrict__ H,
                                               float* __restrict__ out) {
    const int b   = blockIdx.x;
    const int tz  = blockIdx.y;
    const int tid = threadIdx.x;
    const int ts  = tz ? 512 : FADE_S;
    const int te  = tz ? FADE_E : 512;
    const int nt  = te - ts;                   // 25 rows each

    __shared__ float2 tab[32][NB];
    for (int i = tid; i < nt * NB; i += 512) {
        int t = i >> 4, j = i & 15;
        int idx = (KB[j] * (ts + t)) & (T_LEN - 1);
        float ss, cc; sincosf(ANG_STEP * (float)idx, &ss, &cc);
        tab[t][j] = make_float2(cc, ss);
    }

    float er[NB], ei[NB], lr[NB], li[NB];
    const float* hp = H + (size_t)b * 64 * VV + tid;
#pragma unroll
    for (int j = 0; j < NB; ++j) {
        er[j] = hp[(size_t)j        * VV];
        ei[j] = hp[(size_t)(16 + j) * VV];
        lr[j] = hp[(size_t)(32 + j) * VV];
        li[j] = hp[(size_t)(48 + j) * VV];
    }
    __syncthreads();

    const float* xrd = x + ((size_t)b * T_LEN + ts) * VV + tid;
    float*       ow  = out + ((size_t)b * T_LEN + ts) * VV + tid;

    for (int t = 0; t < nt; ++t) {
        float av = xrd[(size_t)t * VV];
        const int tg = ts + t;
        float se = 0.f, sl = 0.f;
#pragma unroll
        for (int j = 0; j < NB; ++j) {
            float2 cs = tab[t][j];
            se = fmaf(er[j], cs.x, se); se = fmaf(ei[j], cs.y, se);
            sl = fmaf(lr[j], cs.x, sl); sl = fmaf(li[j], cs.y, sl);
        }
        float w = 1.0f - (float)(tg - FADE_S) * (1.0f / 50.0f);
        ow[(size_t)t * VV] = av + fmaf(w, se - sl, sl);
    }
}

extern "C" void kernel_launch(void* const* d_in, const int* in_sizes, int n_in,
                              void* d_out, int out_size, void* d_ws, size_t ws_size,
                              hipStream_t stream) {
    (void)in_sizes; (void)n_in; (void)out_size;
    const float* x   = (const float*)d_in[0];
    const float* ger = (const float*)d_in[1];
    const float* gei = (const float*)d_in[2];
    const float* glr = (const float*)d_in[3];
    const float* gli = (const float*)d_in[4];
    float* out = (float*)d_out;

    // ws layout: partials | H. Prefer 16 chunks (grid (BB,8), TLEN=128);
    // fall back to 8 chunks (grid (BB,4), TLEN=256) if ws is small.
    const size_t hflts = (size_t)BB * 64 * VV;
    int tcx;
    if (((size_t)BB * 16 * 32 * VV + hflts) * sizeof(float) <= ws_size) tcx = 16;
    else                                                                tcx = 8;

    float* xpart = (float*)d_ws;
    float* H     = xpart + (size_t)BB * tcx * 32 * VV;

    if (tcx == 16) k_dft_partial<128><<<dim3(BB, 8), 256, 0, stream>>>(x, xpart, 16);
    else           k_dft_partial<256><<<dim3(BB, 4), 256, 0, stream>>>(x, xpart, 8);

    k_combine<<<dim3(BB, NB), 256, 0, stream>>>(xpart, ger, gei, glr, gli, H, tcx);
    k_apply<<<dim3(BB, 16), 128, 0, stream>>>(x, H, out);
    k_fixup<<<dim3(BB, 2), 512, 0, stream>>>(x, H, out);
}